// Round 7
// baseline (489.776 us; speedup 1.0000x reference)
//
#include <hip/hip_runtime.h>
#include <hip/hip_bf16.h>

#define B_   8
#define C_   128
#define H_   96
#define W_   96
#define HP_  98            // padded H/W
#define HO_  48
#define N_   2304          // HO_*HO_
#define K_CONV 1152        // C_*9
#define PLANE_IN  9216     // H_*W_
#define TOT_OUT (B_*C_*N_)

typedef __attribute__((ext_vector_type(8))) short          s16x8;
typedef __attribute__((ext_vector_type(8))) unsigned short u16x8;
typedef __attribute__((ext_vector_type(4))) unsigned short u16x4;
typedef __attribute__((ext_vector_type(4))) float          f32x4;

// XOR-swizzled byte offset for [row][64k] bf16 LDS tiles (128 B rows, 16 B granules)
#define SW8(row, q)  (((row) << 7) + ((((q) ^ ((row) & 7))) << 4))

__device__ __forceinline__ ushort f2bf(float f) {
  __hip_bfloat16 h = __float2bfloat16(f);
  return *reinterpret_cast<ushort*>(&h);
}

__device__ __forceinline__ float block_reduce_sum_256(float v) {
  #pragma unroll
  for (int o = 32; o > 0; o >>= 1) v += __shfl_down(v, o, 64);
  __shared__ float r[4];
  int lane = threadIdx.x & 63, wv = threadIdx.x >> 6;
  if (lane == 0) r[wv] = v;
  __syncthreads();
  float s = 0.f;
  if (threadIdx.x == 0) s = r[0] + r[1] + r[2] + r[3];
  __syncthreads();
  return s;  // valid on thread 0 only
}

// ---------------- BN param prep ---------------------------------------------
__global__ void k_prep(const float* __restrict__ w, const float* __restrict__ bb,
                       const float* __restrict__ m, const float* __restrict__ v,
                       float* __restrict__ inv, float* __restrict__ beta) {
  int c = threadIdx.x;
  if (c < C_) {
    float iv = w[c] / sqrtf(v[c] + 1e-5f);
    inv[c] = iv;
    beta[c] = bb[c] - m[c] * iv;
  }
}

// ---------------- conv weights fp32 OIHW -> bf16 [co][(kh*3+kw)*128+ci] -----
__global__ __launch_bounds__(256) void k_prep_w(const float* __restrict__ w,
                                                ushort* __restrict__ wb) {
  int id = blockIdx.x * 256 + threadIdx.x;
  if (id >= C_ * K_CONV) return;
  int co = id / K_CONV, rem = id - co * K_CONV;
  int tap = rem >> 7, ci = rem & 127;
  wb[id] = f2bf(w[co * K_CONV + ci * 9 + tap]);
}

// ---------------- x -> 3x padded NHWC bf16 y (BN+ReLU fused) ----------------
__global__ __launch_bounds__(256) void k_prep_y(const float* __restrict__ x,
                                                const float* __restrict__ pinv,
                                                const float* __restrict__ pbeta,
                                                ushort* __restrict__ y0,
                                                ushort* __restrict__ y1,
                                                ushort* __restrict__ y2) {
  const int h1 = blockIdx.x, b = blockIdx.y, t = threadIdx.x;
  ushort* ys[3] = {y0 + (size_t)b * HP_ * HP_ * C_,
                   y1 + (size_t)b * HP_ * HP_ * C_,
                   y2 + (size_t)b * HP_ * HP_ * C_};
  u16x8 zer = (u16x8)0;
  if (h1 == 0 || h1 == HP_ - 1) {
    for (int p = 0; p < 3; ++p)
      for (int g = t; g < HP_ * C_ / 8; g += 256)
        *(u16x8*)(ys[p] + (size_t)h1 * HP_ * C_ + g * 8) = zer;
    return;
  }
  __shared__ float xs[128][97];
  const int h = h1 - 1;
  const float* xb = x + (size_t)b * C_ * PLANE_IN + h * W_;
  for (int id = t; id < 128 * 24; id += 256) {
    int ci = id / 24, w4 = id - ci * 24;
    float4 v = *(const float4*)(xb + (size_t)ci * PLANE_IN + w4 * 4);
    xs[ci][w4 * 4 + 0] = v.x; xs[ci][w4 * 4 + 1] = v.y;
    xs[ci][w4 * 4 + 2] = v.z; xs[ci][w4 * 4 + 3] = v.w;
  }
  __syncthreads();
  if (t < 32) {
    int side = t >> 4, cg = t & 15;
    for (int p = 0; p < 3; ++p)
      *(u16x8*)(ys[p] + ((size_t)h1 * HP_ + (side ? HP_ - 1 : 0)) * C_ + cg * 8) = zer;
  }
  for (int p = 0; p < 3; ++p) {
    const float* inv = pinv + p * 128;
    const float* bet = pbeta + p * 128;
    for (int g = t; g < 96 * 16; g += 256) {
      int wdx = g >> 4, cg = g & 15;
      u16x8 o;
      #pragma unroll
      for (int k = 0; k < 8; ++k) {
        int ci = cg * 8 + k;
        o[k] = f2bf(fmaxf(xs[ci][wdx] * inv[ci] + bet[ci], 0.f));
      }
      *(u16x8*)(ys[p] + ((size_t)h1 * HP_ + (wdx + 1)) * C_ + cg * 8) = o;
    }
  }
}

// ---------------- wx = relu(mean_{hw} x) ------------------------------------
__global__ __launch_bounds__(256) void k_meanx(const float* __restrict__ x,
                                               float* __restrict__ wcat) {
  int bc = blockIdx.x;
  const float* p = x + (size_t)bc * PLANE_IN;
  float s = 0.f;
  for (int i = threadIdx.x; i < PLANE_IN; i += 256) s += p[i];
  s = block_reduce_sum_256(s);
  if (threadIdx.x == 0) {
    int b = bc >> 7, c = bc & 127;
    wcat[b * 256 + c] = fmaxf(s * (1.f / PLANE_IN), 0.f);
  }
}

// ---------------- merged MFMA conv (3 branches), direct-global fragments ----
// grid (36, 3, 8). branch 0,1 -> out[b][n][c] (f,g); branch 2 -> out[b][c][n] (h)
__global__ __launch_bounds__(256) void k_conv3(
    const ushort* __restrict__ y0, const ushort* __restrict__ y1, const ushort* __restrict__ y2,
    const ushort* __restrict__ w0, const ushort* __restrict__ w1, const ushort* __restrict__ w2,
    const float* __restrict__ bi0, const float* __restrict__ bi1, const float* __restrict__ bi2,
    ushort* __restrict__ fo, ushort* __restrict__ go, ushort* __restrict__ ho) {
  __shared__ __align__(16) ushort tb[8192];   // epilogue bounce only (16 KB)
  const int br = blockIdx.y, b = blockIdx.z, n0 = blockIdx.x * 64;
  const int t = threadIdx.x, l = t & 63, w = t >> 6, lo = l & 15, quad = l >> 4;
  const ushort* yb = (br == 0 ? y0 : br == 1 ? y1 : y2) + (size_t)b * HP_ * HP_ * C_;
  const ushort* wb = (br == 0 ? w0 : br == 1 ? w1 : w2);
  const float* bias = (br == 0 ? bi0 : br == 1 ? bi1 : bi2);
  const int mh = (w & 1) * 64, nh = (w >> 1) * 32;
  int hb2[2], wb2[2];
  #pragma unroll
  for (int j = 0; j < 2; ++j) {
    int n = n0 + nh + j * 16 + lo;
    int oh = n / HO_, ow = n - oh * HO_;
    hb2[j] = 2 * oh; wb2[j] = 2 * ow;
  }
  f32x4 acc[4][2];
  #pragma unroll
  for (int i = 0; i < 4; ++i)
    #pragma unroll
    for (int j = 0; j < 2; ++j) acc[i][j] = (f32x4)0.f;

  #pragma unroll 4
  for (int k0 = 0; k0 < K_CONV; k0 += 32) {
    int tap = k0 >> 7, ci0 = k0 & 127;
    int kh = tap / 3, kw = tap - kh * 3;
    s16x8 af[4], bf[2];
    #pragma unroll
    for (int i = 0; i < 4; ++i)
      af[i] = *(const s16x8*)(wb + (size_t)(mh + i * 16 + lo) * K_CONV + k0 + quad * 8);
    #pragma unroll
    for (int j = 0; j < 2; ++j)
      bf[j] = *(const s16x8*)(yb + ((size_t)(hb2[j] + kh) * HP_ + (wb2[j] + kw)) * C_ + ci0 + quad * 8);
    #pragma unroll
    for (int i = 0; i < 4; ++i)
      #pragma unroll
      for (int j = 0; j < 2; ++j)
        acc[i][j] = __builtin_amdgcn_mfma_f32_16x16x32_bf16(af[i], bf[j], acc[i][j], 0, 0, 0);
  }

  if (br < 2) {  // out[b][n][c] via LDS bounce
    ushort* out = (br == 0) ? fo : go;
    #pragma unroll
    for (int i = 0; i < 4; ++i) {
      int co4 = mh + i * 16 + quad * 4;
      float4 bi = *(const float4*)&bias[co4];
      float bia[4] = {bi.x, bi.y, bi.z, bi.w};
      #pragma unroll
      for (int j = 0; j < 2; ++j) {
        int pp = nh + j * 16 + lo;
        #pragma unroll
        for (int r = 0; r < 4; ++r)
          tb[pp * 128 + co4 + r] = f2bf(acc[i][j][r] + bia[r]);
      }
    }
    __syncthreads();
    #pragma unroll
    for (int it = 0; it < 4; ++it) {
      int g = t + it * 256;
      int row = g >> 4, gg = g & 15;
      u16x8 d = *(const u16x8*)(tb + row * 128 + gg * 8);
      *(u16x8*)(out + ((size_t)b * N_ + n0 + row) * C_ + gg * 8) = d;
    }
  } else {       // out[b][c][n] via LDS bounce
    #pragma unroll
    for (int i = 0; i < 4; ++i) {
      int co4 = mh + i * 16 + quad * 4;
      float4 bi = *(const float4*)&bias[co4];
      float bia[4] = {bi.x, bi.y, bi.z, bi.w};
      #pragma unroll
      for (int j = 0; j < 2; ++j) {
        int pp = nh + j * 16 + lo;
        #pragma unroll
        for (int r = 0; r < 4; ++r)
          tb[(co4 + r) * 64 + pp] = f2bf(acc[i][j][r] + bia[r]);
      }
    }
    __syncthreads();
    for (int g = t; g < 1024; g += 256) {
      int co = g >> 3, off2 = (g & 7) * 8;
      u16x8 d = *(const u16x8*)(tb + co * 64 + off2);
      *(u16x8*)(ho + ((size_t)b * C_ + co) * N_ + n0 + off2) = d;
    }
  }
}

// ---------------- pass 1: row stats mx[n], l[n] -- no LDS, no barriers ------
// wave w covers n rows n0+w*16..+15; f frags held in regs; g frags direct global
__global__ __launch_bounds__(256) void k_stats(const ushort* __restrict__ f,
                                               const ushort* __restrict__ g,
                                               float2* __restrict__ stats) {
  const int b = blockIdx.y, n0 = blockIdx.x * 64;
  const int t = threadIdx.x, l = t & 63, w = t >> 6, lo = l & 15, quad = l >> 4;
  const ushort* fb = f + (size_t)b * N_ * C_;
  const ushort* gb = g + (size_t)b * N_ * C_;
  s16x8 af[4];
  #pragma unroll
  for (int ks = 0; ks < 4; ++ks)
    af[ks] = *(const s16x8*)(fb + (size_t)(n0 + w * 16 + lo) * C_ + (ks * 4 + quad) * 8);
  float mx[4], lr[4];
  #pragma unroll
  for (int r = 0; r < 4; ++r) { mx[r] = -1e30f; lr[r] = 0.f; }

  #pragma unroll 2
  for (int m0 = 0; m0 < N_; m0 += 64) {
    s16x8 bf[4][4];
    #pragma unroll
    for (int j = 0; j < 4; ++j)
      #pragma unroll
      for (int ks = 0; ks < 4; ++ks)
        bf[j][ks] = *(const s16x8*)(gb + (size_t)(m0 + j * 16 + lo) * C_ + (ks * 4 + quad) * 8);
    f32x4 acc[4];
    #pragma unroll
    for (int j = 0; j < 4; ++j) acc[j] = (f32x4)0.f;
    #pragma unroll
    for (int ks = 0; ks < 4; ++ks)
      #pragma unroll
      for (int j = 0; j < 4; ++j)
        acc[j] = __builtin_amdgcn_mfma_f32_16x16x32_bf16(af[ks], bf[j][ks], acc[j], 0, 0, 0);
    #pragma unroll
    for (int r = 0; r < 4; ++r) {
      float vmax = fmaxf(fmaxf(acc[0][r], acc[1][r]), fmaxf(acc[2][r], acc[3][r]));
      #pragma unroll
      for (int o = 1; o < 16; o <<= 1) vmax = fmaxf(vmax, __shfl_xor(vmax, o, 64));
      float mn = fmaxf(mx[r], vmax);
      float se = __expf(acc[0][r] - mn) + __expf(acc[1][r] - mn) +
                 __expf(acc[2][r] - mn) + __expf(acc[3][r] - mn);
      #pragma unroll
      for (int o = 1; o < 16; o <<= 1) se += __shfl_xor(se, o, 64);
      lr[r] = lr[r] * __expf(mx[r] - mn) + se;
      mx[r] = mn;
    }
  }
  if (lo == 0) {
    #pragma unroll
    for (int r = 0; r < 4; ++r)
      stats[(size_t)b * N_ + n0 + w * 16 + quad * 4 + r] = make_float2(mx[r], lr[r]);
  }
}

// ---------------- pass 2: fused scores+softmax+PV, pT double-buffered -------
__global__ __launch_bounds__(256) void k_attn_out(const ushort* __restrict__ f,
                                                  const ushort* __restrict__ g,
                                                  const ushort* __restrict__ h,
                                                  const float2* __restrict__ stats,
                                                  const float* __restrict__ gammap,
                                                  float* __restrict__ sout) {
  __shared__ __align__(16) char smem[35072];  // pT 2x8KB; epilogue 128x68 f32 = 34816
  const int b = blockIdx.y, m0 = blockIdx.x * 64;
  const int t = threadIdx.x, l = t & 63, w = t >> 6, lo = l & 15, quad = l >> 4;
  const ushort* fb = f + (size_t)b * N_ * C_;
  const ushort* gb = g + (size_t)b * N_ * C_;
  const ushort* hb = h + (size_t)b * C_ * N_;
  const float2* stb = stats + (size_t)b * N_;
  s16x8 bg[4][4];   // g frags, rows m0+j*16+lo, held all kernel
  #pragma unroll
  for (int j = 0; j < 4; ++j)
    #pragma unroll
    for (int ks = 0; ks < 4; ++ks)
      bg[j][ks] = *(const s16x8*)(gb + (size_t)(m0 + j * 16 + lo) * C_ + (ks * 4 + quad) * 8);
  f32x4 accs[2][4];
  #pragma unroll
  for (int i = 0; i < 2; ++i)
    #pragma unroll
    for (int j = 0; j < 4; ++j) accs[i][j] = (f32x4)0.f;

  #pragma unroll 2
  for (int nb = 0; nb < N_; nb += 64) {
    char* pT = smem + (((nb >> 6) & 1) << 13);
    // direct-global fragments for this n-slab
    s16x8 af[4], ah[2][2];
    #pragma unroll
    for (int ks = 0; ks < 4; ++ks)
      af[ks] = *(const s16x8*)(fb + (size_t)(nb + w * 16 + lo) * C_ + (ks * 4 + quad) * 8);
    #pragma unroll
    for (int i = 0; i < 2; ++i)
      #pragma unroll
      for (int ks = 0; ks < 2; ++ks)
        ah[i][ks] = *(const s16x8*)(hb + (size_t)((2 * w + i) * 16 + lo) * N_ + nb + (ks * 4 + quad) * 8);
    // scores for n rows w*16..+15
    f32x4 sc[4];
    #pragma unroll
    for (int j = 0; j < 4; ++j) sc[j] = (f32x4)0.f;
    #pragma unroll
    for (int ks = 0; ks < 4; ++ks)
      #pragma unroll
      for (int j = 0; j < 4; ++j)
        sc[j] = __builtin_amdgcn_mfma_f32_16x16x32_bf16(af[ks], bg[j][ks], sc[j], 0, 0, 0);
    float mxr[4], ilr[4];
    #pragma unroll
    for (int r = 0; r < 4; ++r) {
      float2 st = stb[nb + w * 16 + quad * 4 + r];
      mxr[r] = st.x; ilr[r] = 1.f / st.y;
    }
    const int nl = w * 16 + quad * 4;
    #pragma unroll
    for (int j = 0; j < 4; ++j) {
      u16x4 pv;
      #pragma unroll
      for (int r = 0; r < 4; ++r)
        pv[r] = f2bf(__expf(sc[j][r] - mxr[r]) * ilr[r]);
      *(u16x4*)(pT + SW8(j * 16 + lo, nl >> 3) + (nl & 7) * 2) = pv;
    }
    __syncthreads();   // pT visible (double buffer -> only barrier in loop)
    #pragma unroll
    for (int ks = 0; ks < 2; ++ks)
      #pragma unroll
      for (int j = 0; j < 4; ++j) {
        s16x8 bp = *(const s16x8*)(pT + SW8(j * 16 + lo, ks * 4 + quad));
        accs[0][j] = __builtin_amdgcn_mfma_f32_16x16x32_bf16(ah[0][ks], bp, accs[0][j], 0, 0, 0);
        accs[1][j] = __builtin_amdgcn_mfma_f32_16x16x32_bf16(ah[1][ks], bp, accs[1][j], 0, 0, 0);
      }
  }
  __syncthreads();   // all pT reads done before smem reuse
  const float gv = gammap[0];
  float* ss = (float*)smem;   // [128 c][68]
  #pragma unroll
  for (int i = 0; i < 2; ++i) {
    int c0 = (2 * w + i) * 16 + quad * 4;
    #pragma unroll
    for (int j = 0; j < 4; ++j) {
      int m = j * 16 + lo;
      #pragma unroll
      for (int r = 0; r < 4; ++r)
        ss[(c0 + r) * 68 + m] = gv * accs[i][j][r];
    }
  }
  __syncthreads();
  #pragma unroll
  for (int it = 0; it < 8; ++it) {
    int idx = t + it * 256;
    int c = idx >> 4, mq = idx & 15;
    float4 v = *(const float4*)&ss[c * 68 + mq * 4];
    *(float4*)&sout[((size_t)b * C_ + c) * N_ + m0 + mq * 4] = v;
  }
}

// ---------------- ws = relu(mean_m s) ---------------------------------------
__global__ __launch_bounds__(256) void k_means(const float* __restrict__ s,
                                               float* __restrict__ wcat) {
  int bc = blockIdx.x;
  const float* p = s + (size_t)bc * N_;
  float sm = 0.f;
  for (int i = threadIdx.x; i < N_; i += 256) sm += p[i];
  sm = block_reduce_sum_256(sm);
  if (threadIdx.x == 0) {
    int b = bc >> 7, c = bc & 127;
    wcat[b * 256 + 128 + c] = fmaxf(sm * (1.f / N_), 0.f);
  }
}

// ---------------- SE MLP: 256 -> 42 (relu) -> 128 ---------------------------
__global__ __launch_bounds__(128) void k_se(const float* __restrict__ wcat,
                                            const float* __restrict__ cw,
                                            const float* __restrict__ cb,
                                            const float* __restrict__ uw,
                                            const float* __restrict__ ub,
                                            float* __restrict__ se) {
  const int b = blockIdx.x, t = threadIdx.x;
  __shared__ float wc[256];
  __shared__ float s1[42];
  wc[t] = wcat[b * 256 + t];
  wc[128 + t] = wcat[b * 256 + 128 + t];
  __syncthreads();
  if (t < 42) {
    float a = cb[t];
    const float* r = cw + (size_t)t * 256;
    for (int k = 0; k < 256; ++k) a += wc[k] * r[k];
    s1[t] = fmaxf(a, 0.f);
  }
  __syncthreads();
  {
    float a = ub[t];
    const float* r = uw + (size_t)t * 42;
    for (int j = 0; j < 42; ++j) a += s1[j] * r[j];
    se[b * 128 + t] = a;
  }
}

// ---------------- out = (avgpool2x2(x) + s) * (1 + se) ----------------------
__global__ __launch_bounds__(256) void k_final(const float* __restrict__ x,
                                               const float* __restrict__ s,
                                               const float* __restrict__ se,
                                               float* __restrict__ out) {
  int idx = blockIdx.x * 256 + threadIdx.x;
  if (idx >= TOT_OUT) return;
  int m  = idx % N_;
  int bc = idx / N_;
  int oh = m / HO_, ow = m - oh * HO_;
  const float* xp = x + (size_t)bc * PLANE_IN;
  int ih = oh * 2, iw = ow * 2;
  float l = 0.25f * (xp[ih * W_ + iw] + xp[ih * W_ + iw + 1] +
                     xp[(ih + 1) * W_ + iw] + xp[(ih + 1) * W_ + iw + 1]);
  out[idx] = (l + s[idx]) * (1.f + se[bc]);
}

extern "C" void kernel_launch(void* const* d_in, const int* in_sizes, int n_in,
                              void* d_out, int out_size, void* d_ws, size_t ws_size,
                              hipStream_t stream) {
  (void)in_sizes; (void)n_in; (void)out_size; (void)ws_size;
  const float* x    = (const float*)d_in[0];
  const float* bnw[3] = {(const float*)d_in[1],  (const float*)d_in[7],  (const float*)d_in[13]};
  const float* bnb[3] = {(const float*)d_in[2],  (const float*)d_in[8],  (const float*)d_in[14]};
  const float* bnm[3] = {(const float*)d_in[3],  (const float*)d_in[9],  (const float*)d_in[15]};
  const float* bnv[3] = {(const float*)d_in[4],  (const float*)d_in[10], (const float*)d_in[16]};
  const float* cw_[3] = {(const float*)d_in[5],  (const float*)d_in[11], (const float*)d_in[17]};
  const float* cbb[3] = {(const float*)d_in[6],  (const float*)d_in[12], (const float*)d_in[18]};
  const float* secw = (const float*)d_in[19];
  const float* secb = (const float*)d_in[20];
  const float* seuw = (const float*)d_in[21];
  const float* seub = (const float*)d_in[22];
  const float* gamma = (const float*)d_in[23];
  float* out = (float*)d_out;

  char* ws = (char*)d_ws;
  size_t off = 0;
  auto alloc = [&](size_t bytes) -> char* {
    char* p = ws + off;
    off = (off + bytes + 255) & ~(size_t)255;
    return p;
  };
  ushort* yp[3];
  for (int p = 0; p < 3; ++p) yp[p] = (ushort*)alloc((size_t)B_ * HP_ * HP_ * C_ * 2);
  ushort* wb[3];
  for (int p = 0; p < 3; ++p) wb[p] = (ushort*)alloc((size_t)C_ * K_CONV * 2);
  ushort* fbuf = (ushort*)alloc((size_t)B_ * N_ * C_ * 2);       // [b][n][c]
  ushort* gbuf = (ushort*)alloc((size_t)B_ * N_ * C_ * 2);       // [b][n][c]
  ushort* hbuf = (ushort*)alloc((size_t)B_ * C_ * N_ * 2);       // [b][c][n]
  float2* stats = (float2*)alloc((size_t)B_ * N_ * 8);           // mx, l per row
  float*  sbuf = (float*)alloc((size_t)B_ * C_ * N_ * 4);        // [b][c][n]
  float*  wcat = (float*)alloc(B_ * 256 * 4);
  float*  sebuf = (float*)alloc(B_ * 128 * 4);
  float*  pinv  = (float*)alloc(3 * 128 * 4);
  float*  pbeta = (float*)alloc(3 * 128 * 4);

  for (int p = 0; p < 3; ++p)
    k_prep<<<1, 128, 0, stream>>>(bnw[p], bnb[p], bnm[p], bnv[p], pinv + p * 128, pbeta + p * 128);
  for (int p = 0; p < 3; ++p)
    k_prep_w<<<(C_ * K_CONV + 255) / 256, 256, 0, stream>>>(cw_[p], wb[p]);
  k_prep_y<<<dim3(HP_, B_), 256, 0, stream>>>(x, pinv, pbeta, yp[0], yp[1], yp[2]);

  k_meanx<<<B_ * C_, 256, 0, stream>>>(x, wcat);

  k_conv3<<<dim3(N_ / 64, 3, B_), 256, 0, stream>>>(yp[0], yp[1], yp[2],
                                                    wb[0], wb[1], wb[2],
                                                    cbb[0], cbb[1], cbb[2],
                                                    fbuf, gbuf, hbuf);

  k_stats<<<dim3(N_ / 64, B_), 256, 0, stream>>>(fbuf, gbuf, stats);
  k_attn_out<<<dim3(N_ / 64, B_), 256, 0, stream>>>(fbuf, gbuf, hbuf, stats, gamma, sbuf);

  k_means<<<B_ * C_, 256, 0, stream>>>(sbuf, wcat);
  k_se<<<B_, 128, 0, stream>>>(wcat, secw, secb, seuw, seub, sebuf);

  k_final<<<(TOT_OUT + 255) / 256, 256, 0, stream>>>(x, sbuf, sebuf, out);
}

// Round 8
// 306.780 us; speedup vs baseline: 1.5965x; 1.5965x over previous
//
#include <hip/hip_runtime.h>
#include <hip/hip_bf16.h>

#define B_   8
#define C_   128
#define H_   96
#define W_   96
#define HP_  98            // padded H/W
#define HO_  48
#define N_   2304          // HO_*HO_
#define K_CONV 1152        // C_*9
#define PLANE_IN  9216     // H_*W_
#define TOT_OUT (B_*C_*N_)

typedef __attribute__((ext_vector_type(8))) short          s16x8;
typedef __attribute__((ext_vector_type(8))) unsigned short u16x8;
typedef __attribute__((ext_vector_type(4))) unsigned short u16x4;
typedef __attribute__((ext_vector_type(4))) float          f32x4;

// XOR-swizzled byte offsets for bf16 LDS tiles, 16 B granules
#define SW(row, q)   (((row) << 6) + ((((q) ^ (((row) >> 1) & 3))) << 4))   // 64 B rows
#define SW8(row, q)  (((row) << 7) + ((((q) ^ ((row) & 7))) << 4))           // 128 B rows
#define SW16(row, q) (((row) << 8) + ((((q) ^ ((row) & 15))) << 4))          // 256 B rows

__device__ __forceinline__ ushort f2bf(float f) {
  __hip_bfloat16 h = __float2bfloat16(f);
  return *reinterpret_cast<ushort*>(&h);
}

__device__ __forceinline__ float block_reduce_sum_256(float v) {
  #pragma unroll
  for (int o = 32; o > 0; o >>= 1) v += __shfl_down(v, o, 64);
  __shared__ float r[4];
  int lane = threadIdx.x & 63, wv = threadIdx.x >> 6;
  if (lane == 0) r[wv] = v;
  __syncthreads();
  float s = 0.f;
  if (threadIdx.x == 0) s = r[0] + r[1] + r[2] + r[3];
  __syncthreads();
  return s;  // valid on thread 0 only
}

// ---------------- BN param prep (3 branches in one dispatch) ----------------
__global__ void k_prep(const float* __restrict__ w0, const float* __restrict__ b0,
                       const float* __restrict__ m0, const float* __restrict__ v0,
                       const float* __restrict__ w1, const float* __restrict__ b1,
                       const float* __restrict__ m1, const float* __restrict__ v1,
                       const float* __restrict__ w2, const float* __restrict__ b2,
                       const float* __restrict__ m2, const float* __restrict__ v2,
                       float* __restrict__ inv, float* __restrict__ beta) {
  int p = blockIdx.x, c = threadIdx.x;
  const float* w = (p == 0 ? w0 : p == 1 ? w1 : w2);
  const float* bb = (p == 0 ? b0 : p == 1 ? b1 : b2);
  const float* m = (p == 0 ? m0 : p == 1 ? m1 : m2);
  const float* v = (p == 0 ? v0 : p == 1 ? v1 : v2);
  if (c < C_) {
    float iv = w[c] / sqrtf(v[c] + 1e-5f);
    inv[p * 128 + c] = iv;
    beta[p * 128 + c] = bb[c] - m[c] * iv;
  }
}

// ------- conv weights fp32 OIHW -> bf16 [co][(kh*3+kw)*128+ci], 3 branches --
__global__ __launch_bounds__(256) void k_prep_w(const float* __restrict__ w0,
                                                const float* __restrict__ w1,
                                                const float* __restrict__ w2,
                                                ushort* __restrict__ o0,
                                                ushort* __restrict__ o1,
                                                ushort* __restrict__ o2) {
  int p = blockIdx.y;
  const float* w = (p == 0 ? w0 : p == 1 ? w1 : w2);
  ushort* wb = (p == 0 ? o0 : p == 1 ? o1 : o2);
  int id = blockIdx.x * 256 + threadIdx.x;
  if (id >= C_ * K_CONV) return;
  int co = id / K_CONV, rem = id - co * K_CONV;
  int tap = rem >> 7, ci = rem & 127;
  wb[id] = f2bf(w[co * K_CONV + ci * 9 + tap]);
}

// ---------------- x -> 3x padded NHWC bf16 y (BN+ReLU fused) ----------------
__global__ __launch_bounds__(256) void k_prep_y(const float* __restrict__ x,
                                                const float* __restrict__ pinv,
                                                const float* __restrict__ pbeta,
                                                ushort* __restrict__ y0,
                                                ushort* __restrict__ y1,
                                                ushort* __restrict__ y2) {
  const int h1 = blockIdx.x, b = blockIdx.y, t = threadIdx.x;
  ushort* ys[3] = {y0 + (size_t)b * HP_ * HP_ * C_,
                   y1 + (size_t)b * HP_ * HP_ * C_,
                   y2 + (size_t)b * HP_ * HP_ * C_};
  u16x8 zer = (u16x8)0;
  if (h1 == 0 || h1 == HP_ - 1) {
    for (int p = 0; p < 3; ++p)
      for (int g = t; g < HP_ * C_ / 8; g += 256)
        *(u16x8*)(ys[p] + (size_t)h1 * HP_ * C_ + g * 8) = zer;
    return;
  }
  __shared__ float xs[128][97];
  const int h = h1 - 1;
  const float* xb = x + (size_t)b * C_ * PLANE_IN + h * W_;
  for (int id = t; id < 128 * 24; id += 256) {
    int ci = id / 24, w4 = id - ci * 24;
    float4 v = *(const float4*)(xb + (size_t)ci * PLANE_IN + w4 * 4);
    xs[ci][w4 * 4 + 0] = v.x; xs[ci][w4 * 4 + 1] = v.y;
    xs[ci][w4 * 4 + 2] = v.z; xs[ci][w4 * 4 + 3] = v.w;
  }
  __syncthreads();
  if (t < 32) {
    int side = t >> 4, cg = t & 15;
    for (int p = 0; p < 3; ++p)
      *(u16x8*)(ys[p] + ((size_t)h1 * HP_ + (side ? HP_ - 1 : 0)) * C_ + cg * 8) = zer;
  }
  for (int p = 0; p < 3; ++p) {
    const float* inv = pinv + p * 128;
    const float* bet = pbeta + p * 128;
    for (int g = t; g < 96 * 16; g += 256) {
      int wdx = g >> 4, cg = g & 15;
      u16x8 o;
      #pragma unroll
      for (int k = 0; k < 8; ++k) {
        int ci = cg * 8 + k;
        o[k] = f2bf(fmaxf(xs[ci][wdx] * inv[ci] + bet[ci], 0.f));
      }
      *(u16x8*)(ys[p] + ((size_t)h1 * HP_ + (wdx + 1)) * C_ + cg * 8) = o;
    }
  }
}

// ---------------- wx = relu(mean_{hw} x) ------------------------------------
__global__ __launch_bounds__(256) void k_meanx(const float* __restrict__ x,
                                               float* __restrict__ wcat) {
  int bc = blockIdx.x;
  const float* p = x + (size_t)bc * PLANE_IN;
  float s = 0.f;
  for (int i = threadIdx.x; i < PLANE_IN; i += 256) s += p[i];
  s = block_reduce_sum_256(s);
  if (threadIdx.x == 0) {
    int b = bc >> 7, c = bc & 127;
    wcat[b * 256 + c] = fmaxf(s * (1.f / PLANE_IN), 0.f);
  }
}

// ------- merged LDS-staged MFMA conv (3 branches): grid (36, 3, 8) ----------
// br 0,1 -> out[b][n][c] (f,g); br 2 -> out[b][c][n] (h)
__global__ __launch_bounds__(256) void k_conv3(
    const ushort* __restrict__ y0, const ushort* __restrict__ y1, const ushort* __restrict__ y2,
    const ushort* __restrict__ w0, const ushort* __restrict__ w1, const ushort* __restrict__ w2,
    const float* __restrict__ bi0, const float* __restrict__ bi1, const float* __restrict__ bi2,
    ushort* __restrict__ fo, ushort* __restrict__ go, ushort* __restrict__ ho) {
  __shared__ __align__(16) char smem[16384];
  char* As = smem;          // 128 rows x 64 B (swizzled)
  char* Bs = smem + 8192;   // 64 rows x 64 B (swizzled)
  const int br = blockIdx.y, b = blockIdx.z, n0 = blockIdx.x * 64;
  const int t = threadIdx.x, l = t & 63, w = t >> 6;
  const ushort* yb = (br == 0 ? y0 : br == 1 ? y1 : y2) + (size_t)b * HP_ * HP_ * C_;
  const ushort* wb = (br == 0 ? w0 : br == 1 ? w1 : w2);
  const float* bias = (br == 0 ? bi0 : br == 1 ? bi1 : bi2);
  const int pos = t >> 2, q = t & 3;
  const int n_glob = n0 + pos;
  const int oh = n_glob / HO_, ow = n_glob - oh * HO_;
  const int mh = (w & 1) * 64, nh = (w >> 1) * 32;
  f32x4 acc[4][2];
  #pragma unroll
  for (int i = 0; i < 4; ++i)
    #pragma unroll
    for (int j = 0; j < 2; ++j) acc[i][j] = (f32x4)0.f;

  for (int k0 = 0; k0 < K_CONV; k0 += 32) {
    int tap = k0 >> 7, ci0 = k0 & 127;
    int kh = tap / 3, kw = tap - kh * 3;
    #pragma unroll
    for (int g2 = 0; g2 < 2; ++g2) {   // A: 512 granules
      int g = t + g2 * 256, row = g >> 2, qq = g & 3;
      u16x8 d = *(const u16x8*)(wb + row * K_CONV + k0 + qq * 8);
      *(u16x8*)(As + SW(row, qq)) = d;
    }
    {   // B: 256 granules
      int h1 = 2 * oh + kh, w1 = 2 * ow + kw;
      u16x8 d = *(const u16x8*)(yb + ((size_t)h1 * HP_ + w1) * C_ + ci0 + q * 8);
      *(u16x8*)(Bs + SW(pos, q)) = d;
    }
    __syncthreads();
    s16x8 af[4], bf[2];
    #pragma unroll
    for (int i = 0; i < 4; ++i) {
      int r = mh + i * 16 + (l & 15);
      af[i] = *(const s16x8*)(As + SW(r, (l >> 4)));
    }
    #pragma unroll
    for (int j = 0; j < 2; ++j) {
      int r = nh + j * 16 + (l & 15);
      bf[j] = *(const s16x8*)(Bs + SW(r, (l >> 4)));
    }
    #pragma unroll
    for (int i = 0; i < 4; ++i)
      #pragma unroll
      for (int j = 0; j < 2; ++j)
        acc[i][j] = __builtin_amdgcn_mfma_f32_16x16x32_bf16(af[i], bf[j], acc[i][j], 0, 0, 0);
    __syncthreads();
  }

  if (br < 2) {  // out[b][n][c] via LDS bounce
    ushort* out = (br == 0) ? fo : go;
    ushort* tb = (ushort*)smem;  // [64 pos][128 co]
    #pragma unroll
    for (int i = 0; i < 4; ++i) {
      int co4 = mh + i * 16 + (l >> 4) * 4;
      float4 bi = *(const float4*)&bias[co4];
      float bia[4] = {bi.x, bi.y, bi.z, bi.w};
      #pragma unroll
      for (int j = 0; j < 2; ++j) {
        int pp = nh + j * 16 + (l & 15);
        #pragma unroll
        for (int r = 0; r < 4; ++r)
          tb[pp * 128 + co4 + r] = f2bf(acc[i][j][r] + bia[r]);
      }
    }
    __syncthreads();
    #pragma unroll
    for (int it = 0; it < 4; ++it) {
      int g = t + it * 256;
      int row = g >> 4, gg = g & 15;
      u16x8 d = *(const u16x8*)(tb + row * 128 + gg * 8);
      *(u16x8*)(out + ((size_t)b * N_ + n0 + row) * C_ + gg * 8) = d;
    }
  } else {       // out[b][c][n] via LDS bounce
    ushort* tb = (ushort*)smem;  // [co][64 pos]
    #pragma unroll
    for (int i = 0; i < 4; ++i) {
      int co4 = mh + i * 16 + (l >> 4) * 4;
      float4 bi = *(const float4*)&bias[co4];
      float bia[4] = {bi.x, bi.y, bi.z, bi.w};
      #pragma unroll
      for (int j = 0; j < 2; ++j) {
        int pp = nh + j * 16 + (l & 15);
        #pragma unroll
        for (int r = 0; r < 4; ++r)
          tb[(co4 + r) * 64 + pp] = f2bf(acc[i][j][r] + bia[r]);
      }
    }
    __syncthreads();
    for (int g = t; g < 1024; g += 256) {
      int co = g >> 3, off2 = (g & 7) * 8;
      u16x8 d = *(const u16x8*)(tb + co * 64 + off2);
      *(u16x8*)(ho + ((size_t)b * C_ + co) * N_ + n0 + off2) = d;
    }
  }
}

// ------- pass 1: partial row stats over m-chunk; grid (36, 4, 8) ------------
// per-lane online fold in loop (no shfl); cross-lane merge once at end
__global__ __launch_bounds__(256) void k_stats(const ushort* __restrict__ f,
                                               const ushort* __restrict__ g,
                                               float2* __restrict__ pstats) {
  __shared__ __align__(16) char smem[32768];
  char* fs = smem;           // [64 n][128 c] SW16 16 KB (once)
  char* gs = smem + 16384;   // [64 m][128 c] SW16 16 KB (per iter)
  const int b = blockIdx.z, n0 = blockIdx.x * 64, mz = blockIdx.y;
  const int t = threadIdx.x, l = t & 63, w = t >> 6, lo = l & 15, quad = l >> 4;
  const ushort* fb = f + (size_t)b * N_ * C_;
  const ushort* gb = g + (size_t)b * N_ * C_;
  #pragma unroll
  for (int it = 0; it < 4; ++it) {
    int G = t + it * 256, row = G >> 4, g16 = G & 15;
    *(u16x8*)(fs + SW16(row, g16)) = *(const u16x8*)(fb + (size_t)(n0 + row) * C_ + g16 * 8);
  }
  __syncthreads();
  s16x8 af[4];
  #pragma unroll
  for (int ks = 0; ks < 4; ++ks)
    af[ks] = *(const s16x8*)(fs + SW16(w * 16 + lo, ks * 4 + quad));
  float mloc[4], lloc[4];
  #pragma unroll
  for (int r = 0; r < 4; ++r) { mloc[r] = -1e30f; lloc[r] = 0.f; }
  const int m_beg = mz * 576;

  for (int i9 = 0; i9 < 9; ++i9) {
    int m0 = m_beg + i9 * 64;
    __syncthreads();   // prior gs reads complete
    #pragma unroll
    for (int it = 0; it < 4; ++it) {
      int G = t + it * 256, row = G >> 4, g16 = G & 15;
      *(u16x8*)(gs + SW16(row, g16)) = *(const u16x8*)(gb + (size_t)(m0 + row) * C_ + g16 * 8);
    }
    __syncthreads();
    f32x4 acc[4];
    #pragma unroll
    for (int j = 0; j < 4; ++j) acc[j] = (f32x4)0.f;
    #pragma unroll
    for (int ks = 0; ks < 4; ++ks)
      #pragma unroll
      for (int j = 0; j < 4; ++j) {
        s16x8 bf = *(const s16x8*)(gs + SW16(j * 16 + lo, ks * 4 + quad));
        acc[j] = __builtin_amdgcn_mfma_f32_16x16x32_bf16(af[ks], bf, acc[j], 0, 0, 0);
      }
    #pragma unroll
    for (int r = 0; r < 4; ++r) {
      float vmax = fmaxf(fmaxf(acc[0][r], acc[1][r]), fmaxf(acc[2][r], acc[3][r]));
      float mn = fmaxf(mloc[r], vmax);
      lloc[r] = lloc[r] * __expf(mloc[r] - mn) +
                __expf(acc[0][r] - mn) + __expf(acc[1][r] - mn) +
                __expf(acc[2][r] - mn) + __expf(acc[3][r] - mn);
      mloc[r] = mn;
    }
  }
  // cross-lane merge over the 16 lanes sharing a row (xor bits 0..3)
  #pragma unroll
  for (int r = 0; r < 4; ++r) {
    #pragma unroll
    for (int o = 1; o < 16; o <<= 1) {
      float mo = __shfl_xor(mloc[r], o, 64);
      float lo2 = __shfl_xor(lloc[r], o, 64);
      float mn = fmaxf(mloc[r], mo);
      lloc[r] = lloc[r] * __expf(mloc[r] - mn) + lo2 * __expf(mo - mn);
      mloc[r] = mn;
    }
  }
  if (lo == 0) {
    #pragma unroll
    for (int r = 0; r < 4; ++r)
      pstats[((size_t)mz * B_ + b) * N_ + n0 + w * 16 + quad * 4 + r] =
          make_float2(mloc[r], lloc[r]);
  }
}

// ---------------- merge 4 partial stats -> final (mx, l) --------------------
__global__ __launch_bounds__(256) void k_stats_red(const float2* __restrict__ p,
                                                   float2* __restrict__ stats) {
  int idx = blockIdx.x * 256 + threadIdx.x;   // b*N+n
  if (idx >= B_ * N_) return;
  float mx = -1e30f, ls = 0.f;
  #pragma unroll
  for (int z = 0; z < 4; ++z) {
    float2 s = p[(size_t)z * B_ * N_ + idx];
    float mn = fmaxf(mx, s.x);
    ls = ls * __expf(mx - mn) + s.y * __expf(s.x - mn);
    mx = mn;
  }
  stats[idx] = make_float2(mx, ls);
}

// ------- pass 2: fused scores+softmax+PV partials; grid (36, 4, 8) ----------
__global__ __launch_bounds__(256) void k_attn_out(const ushort* __restrict__ f,
                                                  const ushort* __restrict__ g,
                                                  const ushort* __restrict__ h,
                                                  const float2* __restrict__ stats,
                                                  float* __restrict__ spart) {
  __shared__ __align__(16) char smem[35072];  // pT 2x8KB; epilogue 128x68 f32
  const int b = blockIdx.z, m0 = blockIdx.x * 64, nz = blockIdx.y;
  const int t = threadIdx.x, l = t & 63, w = t >> 6, lo = l & 15, quad = l >> 4;
  const ushort* fb = f + (size_t)b * N_ * C_;
  const ushort* gb = g + (size_t)b * N_ * C_;
  const ushort* hb = h + (size_t)b * C_ * N_;
  const float2* stb = stats + (size_t)b * N_;
  s16x8 bg[4][4];   // g frags, rows m0+j*16+lo, held all kernel
  #pragma unroll
  for (int j = 0; j < 4; ++j)
    #pragma unroll
    for (int ks = 0; ks < 4; ++ks)
      bg[j][ks] = *(const s16x8*)(gb + (size_t)(m0 + j * 16 + lo) * C_ + (ks * 4 + quad) * 8);
  f32x4 accs[2][4];
  #pragma unroll
  for (int i = 0; i < 2; ++i)
    #pragma unroll
    for (int j = 0; j < 4; ++j) accs[i][j] = (f32x4)0.f;
  const int n_beg = nz * 576;

  for (int i9 = 0; i9 < 9; ++i9) {
    int nb = n_beg + i9 * 64;
    char* pT = smem + ((i9 & 1) << 13);
    s16x8 af[4], ah[2][2];
    #pragma unroll
    for (int ks = 0; ks < 4; ++ks)
      af[ks] = *(const s16x8*)(fb + (size_t)(nb + w * 16 + lo) * C_ + (ks * 4 + quad) * 8);
    #pragma unroll
    for (int i = 0; i < 2; ++i)
      #pragma unroll
      for (int ks = 0; ks < 2; ++ks)
        ah[i][ks] = *(const s16x8*)(hb + (size_t)((2 * w + i) * 16 + lo) * N_ + nb + (ks * 4 + quad) * 8);
    f32x4 sc[4];
    #pragma unroll
    for (int j = 0; j < 4; ++j) sc[j] = (f32x4)0.f;
    #pragma unroll
    for (int ks = 0; ks < 4; ++ks)
      #pragma unroll
      for (int j = 0; j < 4; ++j)
        sc[j] = __builtin_amdgcn_mfma_f32_16x16x32_bf16(af[ks], bg[j][ks], sc[j], 0, 0, 0);
    float mxr[4], ilr[4];
    #pragma unroll
    for (int r = 0; r < 4; ++r) {
      float2 st = stb[nb + w * 16 + quad * 4 + r];
      mxr[r] = st.x; ilr[r] = 1.f / st.y;
    }
    const int nl = w * 16 + quad * 4;
    #pragma unroll
    for (int j = 0; j < 4; ++j) {
      u16x4 pv;
      #pragma unroll
      for (int r = 0; r < 4; ++r)
        pv[r] = f2bf(__expf(sc[j][r] - mxr[r]) * ilr[r]);
      *(u16x4*)(pT + SW8(j * 16 + lo, nl >> 3) + (nl & 7) * 2) = pv;
    }
    __syncthreads();
    #pragma unroll
    for (int ks = 0; ks < 2; ++ks)
      #pragma unroll
      for (int j = 0; j < 4; ++j) {
        s16x8 bp = *(const s16x8*)(pT + SW8(j * 16 + lo, ks * 4 + quad));
        accs[0][j] = __builtin_amdgcn_mfma_f32_16x16x32_bf16(ah[0][ks], bp, accs[0][j], 0, 0, 0);
        accs[1][j] = __builtin_amdgcn_mfma_f32_16x16x32_bf16(ah[1][ks], bp, accs[1][j], 0, 0, 0);
      }
  }
  __syncthreads();
  float* ss = (float*)smem;   // [128 c][68]
  #pragma unroll
  for (int i = 0; i < 2; ++i) {
    int c0 = (2 * w + i) * 16 + quad * 4;
    #pragma unroll
    for (int j = 0; j < 4; ++j) {
      int m = j * 16 + lo;
      #pragma unroll
      for (int r = 0; r < 4; ++r)
        ss[(c0 + r) * 68 + m] = accs[i][j][r];
    }
  }
  __syncthreads();
  float* outp = spart + (size_t)nz * TOT_OUT + (size_t)b * C_ * N_ + m0;
  #pragma unroll
  for (int it = 0; it < 8; ++it) {
    int idx = t + it * 256;
    int c = idx >> 4, mq = idx & 15;
    float4 v = *(const float4*)&ss[c * 68 + mq * 4];
    *(float4*)&outp[(size_t)c * N_ + mq * 4] = v;
  }
}

// ---------------- sbuf = gamma * sum_z spart[z] -----------------------------
__global__ __launch_bounds__(256) void k_sred(const float* __restrict__ spart,
                                              const float* __restrict__ gammap,
                                              float* __restrict__ sbuf) {
  int idx = blockIdx.x * 256 + threadIdx.x;
  if (idx >= TOT_OUT) return;
  float s = spart[idx] + spart[(size_t)TOT_OUT + idx] +
            spart[2 * (size_t)TOT_OUT + idx] + spart[3 * (size_t)TOT_OUT + idx];
  sbuf[idx] = gammap[0] * s;
}

// ---------------- ws = relu(mean_m s) ---------------------------------------
__global__ __launch_bounds__(256) void k_means(const float* __restrict__ s,
                                               float* __restrict__ wcat) {
  int bc = blockIdx.x;
  const float* p = s + (size_t)bc * N_;
  float sm = 0.f;
  for (int i = threadIdx.x; i < N_; i += 256) sm += p[i];
  sm = block_reduce_sum_256(sm);
  if (threadIdx.x == 0) {
    int b = bc >> 7, c = bc & 127;
    wcat[b * 256 + 128 + c] = fmaxf(sm * (1.f / N_), 0.f);
  }
}

// ---------------- SE MLP: 256 -> 42 (relu) -> 128 ---------------------------
__global__ __launch_bounds__(128) void k_se(const float* __restrict__ wcat,
                                            const float* __restrict__ cw,
                                            const float* __restrict__ cb,
                                            const float* __restrict__ uw,
                                            const float* __restrict__ ub,
                                            float* __restrict__ se) {
  const int b = blockIdx.x, t = threadIdx.x;
  __shared__ float wc[256];
  __shared__ float s1[42];
  wc[t] = wcat[b * 256 + t];
  wc[128 + t] = wcat[b * 256 + 128 + t];
  __syncthreads();
  if (t < 42) {
    float a = cb[t];
    const float* r = cw + (size_t)t * 256;
    for (int k = 0; k < 256; ++k) a += wc[k] * r[k];
    s1[t] = fmaxf(a, 0.f);
  }
  __syncthreads();
  {
    float a = ub[t];
    const float* r = uw + (size_t)t * 42;
    for (int j = 0; j < 42; ++j) a += s1[j] * r[j];
    se[b * 128 + t] = a;
  }
}

// ---------------- out = (avgpool2x2(x) + s) * (1 + se) ----------------------
__global__ __launch_bounds__(256) void k_final(const float* __restrict__ x,
                                               const float* __restrict__ s,
                                               const float* __restrict__ se,
                                               float* __restrict__ out) {
  int idx = blockIdx.x * 256 + threadIdx.x;
  if (idx >= TOT_OUT) return;
  int m  = idx % N_;
  int bc = idx / N_;
  int oh = m / HO_, ow = m - oh * HO_;
  const float* xp = x + (size_t)bc * PLANE_IN;
  int ih = oh * 2, iw = ow * 2;
  float l = 0.25f * (xp[ih * W_ + iw] + xp[ih * W_ + iw + 1] +
                     xp[(ih + 1) * W_ + iw] + xp[(ih + 1) * W_ + iw + 1]);
  out[idx] = (l + s[idx]) * (1.f + se[bc]);
}

extern "C" void kernel_launch(void* const* d_in, const int* in_sizes, int n_in,
                              void* d_out, int out_size, void* d_ws, size_t ws_size,
                              hipStream_t stream) {
  (void)in_sizes; (void)n_in; (void)out_size; (void)ws_size;
  const float* x    = (const float*)d_in[0];
  const float* bnw[3] = {(const float*)d_in[1],  (const float*)d_in[7],  (const float*)d_in[13]};
  const float* bnb[3] = {(const float*)d_in[2],  (const float*)d_in[8],  (const float*)d_in[14]};
  const float* bnm[3] = {(const float*)d_in[3],  (const float*)d_in[9],  (const float*)d_in[15]};
  const float* bnv[3] = {(const float*)d_in[4],  (const float*)d_in[10], (const float*)d_in[16]};
  const float* cw_[3] = {(const float*)d_in[5],  (const float*)d_in[11], (const float*)d_in[17]};
  const float* cbb[3] = {(const float*)d_in[6],  (const float*)d_in[12], (const float*)d_in[18]};
  const float* secw = (const float*)d_in[19];
  const float* secb = (const float*)d_in[20];
  const float* seuw = (const float*)d_in[21];
  const float* seub = (const float*)d_in[22];
  const float* gamma = (const float*)d_in[23];
  float* out = (float*)d_out;

  char* ws = (char*)d_ws;
  size_t off = 0;
  auto alloc = [&](size_t bytes) -> char* {
    char* p = ws + off;
    off = (off + bytes + 255) & ~(size_t)255;
    return p;
  };
  ushort* yp[3];
  for (int p = 0; p < 3; ++p) yp[p] = (ushort*)alloc((size_t)B_ * HP_ * HP_ * C_ * 2);
  ushort* wb[3];
  for (int p = 0; p < 3; ++p) wb[p] = (ushort*)alloc((size_t)C_ * K_CONV * 2);
  ushort* fbuf = (ushort*)alloc((size_t)B_ * N_ * C_ * 2);       // [b][n][c]
  ushort* gbuf = (ushort*)alloc((size_t)B_ * N_ * C_ * 2);       // [b][n][c]
  ushort* hbuf = (ushort*)alloc((size_t)B_ * C_ * N_ * 2);       // [b][c][n]
  float2* pstats = (float2*)alloc((size_t)4 * B_ * N_ * 8);      // partial (mx,l)
  float2* stats  = (float2*)alloc((size_t)B_ * N_ * 8);          // final (mx,l)
  float*  spart = (float*)alloc((size_t)4 * TOT_OUT * 4);        // partial PV sums
  float*  sbuf = (float*)alloc((size_t)TOT_OUT * 4);             // [b][c][n]
  float*  wcat = (float*)alloc(B_ * 256 * 4);
  float*  sebuf = (float*)alloc(B_ * 128 * 4);
  float*  pinv  = (float*)alloc(3 * 128 * 4);
  float*  pbeta = (float*)alloc(3 * 128 * 4);

  k_prep<<<3, 128, 0, stream>>>(bnw[0], bnb[0], bnm[0], bnv[0],
                                bnw[1], bnb[1], bnm[1], bnv[1],
                                bnw[2], bnb[2], bnm[2], bnv[2], pinv, pbeta);
  k_prep_w<<<dim3((C_ * K_CONV + 255) / 256, 3), 256, 0, stream>>>(
      cw_[0], cw_[1], cw_[2], wb[0], wb[1], wb[2]);
  k_prep_y<<<dim3(HP_, B_), 256, 0, stream>>>(x, pinv, pbeta, yp[0], yp[1], yp[2]);
  k_meanx<<<B_ * C_, 256, 0, stream>>>(x, wcat);

  k_conv3<<<dim3(N_ / 64, 3, B_), 256, 0, stream>>>(yp[0], yp[1], yp[2],
                                                    wb[0], wb[1], wb[2],
                                                    cbb[0], cbb[1], cbb[2],
                                                    fbuf, gbuf, hbuf);

  k_stats<<<dim3(N_ / 64, 4, B_), 256, 0, stream>>>(fbuf, gbuf, pstats);
  k_stats_red<<<(B_ * N_ + 255) / 256, 256, 0, stream>>>(pstats, stats);
  k_attn_out<<<dim3(N_ / 64, 4, B_), 256, 0, stream>>>(fbuf, gbuf, hbuf, stats, spart);
  k_sred<<<(TOT_OUT + 255) / 256, 256, 0, stream>>>(spart, gamma, sbuf);

  k_means<<<B_ * C_, 256, 0, stream>>>(sbuf, wcat);
  k_se<<<B_, 128, 0, stream>>>(wcat, secw, secb, seuw, seub, sebuf);

  k_final<<<(TOT_OUT + 255) / 256, 256, 0, stream>>>(x, sbuf, sebuf, out);
}

// Round 9
// 304.511 us; speedup vs baseline: 1.6084x; 1.0075x over previous
//
#include <hip/hip_runtime.h>
#include <hip/hip_bf16.h>

#define B_   8
#define C_   128
#define H_   96
#define W_   96
#define HP_  98            // padded H/W
#define HO_  48
#define N_   2304          // HO_*HO_
#define K_CONV 1152        // C_*9
#define PLANE_IN  9216     // H_*W_
#define TOT_OUT (B_*C_*N_)

typedef __attribute__((ext_vector_type(8))) short          s16x8;
typedef __attribute__((ext_vector_type(8))) unsigned short u16x8;
typedef __attribute__((ext_vector_type(4))) unsigned short u16x4;
typedef __attribute__((ext_vector_type(4))) float          f32x4;

// XOR-swizzled byte offsets for bf16 LDS tiles, 16 B granules
#define SW(row, q)   (((row) << 6) + ((((q) ^ (((row) >> 1) & 3))) << 4))   // 64 B rows
#define SW8(row, q)  (((row) << 7) + ((((q) ^ ((row) & 7))) << 4))           // 128 B rows
#define SW16(row, q) (((row) << 8) + ((((q) ^ ((row) & 15))) << 4))          // 256 B rows

__device__ __forceinline__ ushort f2bf(float f) {
  __hip_bfloat16 h = __float2bfloat16(f);
  return *reinterpret_cast<ushort*>(&h);
}

__device__ __forceinline__ float block_reduce_sum_256(float v) {
  #pragma unroll
  for (int o = 32; o > 0; o >>= 1) v += __shfl_down(v, o, 64);
  __shared__ float r[4];
  int lane = threadIdx.x & 63, wv = threadIdx.x >> 6;
  if (lane == 0) r[wv] = v;
  __syncthreads();
  float s = 0.f;
  if (threadIdx.x == 0) s = r[0] + r[1] + r[2] + r[3];
  __syncthreads();
  return s;  // valid on thread 0 only
}

// ---------------- BN param prep (3 branches in one dispatch) ----------------
__global__ void k_prep(const float* __restrict__ w0, const float* __restrict__ b0,
                       const float* __restrict__ m0, const float* __restrict__ v0,
                       const float* __restrict__ w1, const float* __restrict__ b1,
                       const float* __restrict__ m1, const float* __restrict__ v1,
                       const float* __restrict__ w2, const float* __restrict__ b2,
                       const float* __restrict__ m2, const float* __restrict__ v2,
                       float* __restrict__ inv, float* __restrict__ beta) {
  int p = blockIdx.x, c = threadIdx.x;
  const float* w = (p == 0 ? w0 : p == 1 ? w1 : w2);
  const float* bb = (p == 0 ? b0 : p == 1 ? b1 : b2);
  const float* m = (p == 0 ? m0 : p == 1 ? m1 : m2);
  const float* v = (p == 0 ? v0 : p == 1 ? v1 : v2);
  if (c < C_) {
    float iv = w[c] / sqrtf(v[c] + 1e-5f);
    inv[p * 128 + c] = iv;
    beta[p * 128 + c] = bb[c] - m[c] * iv;
  }
}

// ------- conv weights fp32 OIHW -> bf16 [co][(kh*3+kw)*128+ci], 3 branches --
__global__ __launch_bounds__(256) void k_prep_w(const float* __restrict__ w0,
                                                const float* __restrict__ w1,
                                                const float* __restrict__ w2,
                                                ushort* __restrict__ o0,
                                                ushort* __restrict__ o1,
                                                ushort* __restrict__ o2) {
  int p = blockIdx.y;
  const float* w = (p == 0 ? w0 : p == 1 ? w1 : w2);
  ushort* wb = (p == 0 ? o0 : p == 1 ? o1 : o2);
  int id = blockIdx.x * 256 + threadIdx.x;
  if (id >= C_ * K_CONV) return;
  int co = id / K_CONV, rem = id - co * K_CONV;
  int tap = rem >> 7, ci = rem & 127;
  wb[id] = f2bf(w[co * K_CONV + ci * 9 + tap]);
}

// ---------------- x -> 3x padded NHWC bf16 y (BN+ReLU fused) ----------------
__global__ __launch_bounds__(256) void k_prep_y(const float* __restrict__ x,
                                                const float* __restrict__ pinv,
                                                const float* __restrict__ pbeta,
                                                ushort* __restrict__ y0,
                                                ushort* __restrict__ y1,
                                                ushort* __restrict__ y2) {
  const int h1 = blockIdx.x, b = blockIdx.y, t = threadIdx.x;
  ushort* ys[3] = {y0 + (size_t)b * HP_ * HP_ * C_,
                   y1 + (size_t)b * HP_ * HP_ * C_,
                   y2 + (size_t)b * HP_ * HP_ * C_};
  u16x8 zer = (u16x8)0;
  if (h1 == 0 || h1 == HP_ - 1) {
    for (int p = 0; p < 3; ++p)
      for (int g = t; g < HP_ * C_ / 8; g += 256)
        *(u16x8*)(ys[p] + (size_t)h1 * HP_ * C_ + g * 8) = zer;
    return;
  }
  __shared__ float xs[128][97];
  const int h = h1 - 1;
  const float* xb = x + (size_t)b * C_ * PLANE_IN + h * W_;
  for (int id = t; id < 128 * 24; id += 256) {
    int ci = id / 24, w4 = id - ci * 24;
    float4 v = *(const float4*)(xb + (size_t)ci * PLANE_IN + w4 * 4);
    xs[ci][w4 * 4 + 0] = v.x; xs[ci][w4 * 4 + 1] = v.y;
    xs[ci][w4 * 4 + 2] = v.z; xs[ci][w4 * 4 + 3] = v.w;
  }
  __syncthreads();
  if (t < 32) {
    int side = t >> 4, cg = t & 15;
    for (int p = 0; p < 3; ++p)
      *(u16x8*)(ys[p] + ((size_t)h1 * HP_ + (side ? HP_ - 1 : 0)) * C_ + cg * 8) = zer;
  }
  for (int p = 0; p < 3; ++p) {
    const float* inv = pinv + p * 128;
    const float* bet = pbeta + p * 128;
    for (int g = t; g < 96 * 16; g += 256) {
      int wdx = g >> 4, cg = g & 15;
      u16x8 o;
      #pragma unroll
      for (int k = 0; k < 8; ++k) {
        int ci = cg * 8 + k;
        o[k] = f2bf(fmaxf(xs[ci][wdx] * inv[ci] + bet[ci], 0.f));
      }
      *(u16x8*)(ys[p] + ((size_t)h1 * HP_ + (wdx + 1)) * C_ + cg * 8) = o;
    }
  }
}

// ---------------- wx = relu(mean_{hw} x) ------------------------------------
__global__ __launch_bounds__(256) void k_meanx(const float* __restrict__ x,
                                               float* __restrict__ wcat) {
  int bc = blockIdx.x;
  const float* p = x + (size_t)bc * PLANE_IN;
  float s = 0.f;
  for (int i = threadIdx.x; i < PLANE_IN; i += 256) s += p[i];
  s = block_reduce_sum_256(s);
  if (threadIdx.x == 0) {
    int b = bc >> 7, c = bc & 127;
    wcat[b * 256 + c] = fmaxf(s * (1.f / PLANE_IN), 0.f);
  }
}

// ------- merged LDS-staged MFMA conv (3 branches): grid (36, 3, 8) ----------
// br 0,1 -> out[b][n][c] (f,g); br 2 -> out[b][c][n] (h)
__global__ __launch_bounds__(256) void k_conv3(
    const ushort* __restrict__ y0, const ushort* __restrict__ y1, const ushort* __restrict__ y2,
    const ushort* __restrict__ w0, const ushort* __restrict__ w1, const ushort* __restrict__ w2,
    const float* __restrict__ bi0, const float* __restrict__ bi1, const float* __restrict__ bi2,
    ushort* __restrict__ fo, ushort* __restrict__ go, ushort* __restrict__ ho) {
  __shared__ __align__(16) char smem[16384];
  char* As = smem;          // 128 rows x 64 B (swizzled)
  char* Bs = smem + 8192;   // 64 rows x 64 B (swizzled)
  const int br = blockIdx.y, b = blockIdx.z, n0 = blockIdx.x * 64;
  const int t = threadIdx.x, l = t & 63, w = t >> 6;
  const ushort* yb = (br == 0 ? y0 : br == 1 ? y1 : y2) + (size_t)b * HP_ * HP_ * C_;
  const ushort* wb = (br == 0 ? w0 : br == 1 ? w1 : w2);
  const float* bias = (br == 0 ? bi0 : br == 1 ? bi1 : bi2);
  const int pos = t >> 2, q = t & 3;
  const int n_glob = n0 + pos;
  const int oh = n_glob / HO_, ow = n_glob - oh * HO_;
  const int mh = (w & 1) * 64, nh = (w >> 1) * 32;
  f32x4 acc[4][2];
  #pragma unroll
  for (int i = 0; i < 4; ++i)
    #pragma unroll
    for (int j = 0; j < 2; ++j) acc[i][j] = (f32x4)0.f;

  for (int k0 = 0; k0 < K_CONV; k0 += 32) {
    int tap = k0 >> 7, ci0 = k0 & 127;
    int kh = tap / 3, kw = tap - kh * 3;
    #pragma unroll
    for (int g2 = 0; g2 < 2; ++g2) {   // A: 512 granules
      int g = t + g2 * 256, row = g >> 2, qq = g & 3;
      u16x8 d = *(const u16x8*)(wb + row * K_CONV + k0 + qq * 8);
      *(u16x8*)(As + SW(row, qq)) = d;
    }
    {   // B: 256 granules
      int h1 = 2 * oh + kh, w1 = 2 * ow + kw;
      u16x8 d = *(const u16x8*)(yb + ((size_t)h1 * HP_ + w1) * C_ + ci0 + q * 8);
      *(u16x8*)(Bs + SW(pos, q)) = d;
    }
    __syncthreads();
    s16x8 af[4], bf[2];
    #pragma unroll
    for (int i = 0; i < 4; ++i) {
      int r = mh + i * 16 + (l & 15);
      af[i] = *(const s16x8*)(As + SW(r, (l >> 4)));
    }
    #pragma unroll
    for (int j = 0; j < 2; ++j) {
      int r = nh + j * 16 + (l & 15);
      bf[j] = *(const s16x8*)(Bs + SW(r, (l >> 4)));
    }
    #pragma unroll
    for (int i = 0; i < 4; ++i)
      #pragma unroll
      for (int j = 0; j < 2; ++j)
        acc[i][j] = __builtin_amdgcn_mfma_f32_16x16x32_bf16(af[i], bf[j], acc[i][j], 0, 0, 0);
    __syncthreads();
  }

  if (br < 2) {  // out[b][n][c] via LDS bounce
    ushort* out = (br == 0) ? fo : go;
    ushort* tb = (ushort*)smem;  // [64 pos][128 co]
    #pragma unroll
    for (int i = 0; i < 4; ++i) {
      int co4 = mh + i * 16 + (l >> 4) * 4;
      float4 bi = *(const float4*)&bias[co4];
      float bia[4] = {bi.x, bi.y, bi.z, bi.w};
      #pragma unroll
      for (int j = 0; j < 2; ++j) {
        int pp = nh + j * 16 + (l & 15);
        #pragma unroll
        for (int r = 0; r < 4; ++r)
          tb[pp * 128 + co4 + r] = f2bf(acc[i][j][r] + bia[r]);
      }
    }
    __syncthreads();
    #pragma unroll
    for (int it = 0; it < 4; ++it) {
      int g = t + it * 256;
      int row = g >> 4, gg = g & 15;
      u16x8 d = *(const u16x8*)(tb + row * 128 + gg * 8);
      *(u16x8*)(out + ((size_t)b * N_ + n0 + row) * C_ + gg * 8) = d;
    }
  } else {       // out[b][c][n] via LDS bounce
    ushort* tb = (ushort*)smem;  // [co][64 pos]
    #pragma unroll
    for (int i = 0; i < 4; ++i) {
      int co4 = mh + i * 16 + (l >> 4) * 4;
      float4 bi = *(const float4*)&bias[co4];
      float bia[4] = {bi.x, bi.y, bi.z, bi.w};
      #pragma unroll
      for (int j = 0; j < 2; ++j) {
        int pp = nh + j * 16 + (l & 15);
        #pragma unroll
        for (int r = 0; r < 4; ++r)
          tb[(co4 + r) * 64 + pp] = f2bf(acc[i][j][r] + bia[r]);
      }
    }
    __syncthreads();
    for (int g = t; g < 1024; g += 256) {
      int co = g >> 3, off2 = (g & 7) * 8;
      u16x8 d = *(const u16x8*)(tb + co * 64 + off2);
      *(u16x8*)(ho + ((size_t)b * C_ + co) * N_ + n0 + off2) = d;
    }
  }
}

// ------- pass 1: partial row stats over m-chunk; grid 1152 (XCD swizzle) ----
// b = blk&7 so each XCD's L2 serves one batch (f+g ~1.2 MB < 4 MB)
__global__ __launch_bounds__(256) void k_stats(const ushort* __restrict__ f,
                                               const ushort* __restrict__ g,
                                               float2* __restrict__ pstats) {
  __shared__ __align__(16) char smem[32768];
  char* fs = smem;           // [64 n][128 c] SW16 16 KB (once)
  char* gs = smem + 16384;   // [64 m][128 c] SW16 16 KB (per iter)
  const int blk = blockIdx.x;
  const int b = blk & 7, t2 = blk >> 3;
  const int n0 = (t2 % 36) * 64, mz = t2 / 36;
  const int t = threadIdx.x, l = t & 63, w = t >> 6, lo = l & 15, quad = l >> 4;
  const ushort* fb = f + (size_t)b * N_ * C_;
  const ushort* gb = g + (size_t)b * N_ * C_;
  #pragma unroll
  for (int it = 0; it < 4; ++it) {
    int G = t + it * 256, row = G >> 4, g16 = G & 15;
    *(u16x8*)(fs + SW16(row, g16)) = *(const u16x8*)(fb + (size_t)(n0 + row) * C_ + g16 * 8);
  }
  __syncthreads();
  s16x8 af[4];
  #pragma unroll
  for (int ks = 0; ks < 4; ++ks)
    af[ks] = *(const s16x8*)(fs + SW16(w * 16 + lo, ks * 4 + quad));
  float mloc[4], lloc[4];
  #pragma unroll
  for (int r = 0; r < 4; ++r) { mloc[r] = -1e30f; lloc[r] = 0.f; }
  const int m_beg = mz * 576;

  for (int i9 = 0; i9 < 9; ++i9) {
    int m0 = m_beg + i9 * 64;
    __syncthreads();   // prior gs reads complete
    #pragma unroll
    for (int it = 0; it < 4; ++it) {
      int G = t + it * 256, row = G >> 4, g16 = G & 15;
      *(u16x8*)(gs + SW16(row, g16)) = *(const u16x8*)(gb + (size_t)(m0 + row) * C_ + g16 * 8);
    }
    __syncthreads();
    f32x4 acc[4];
    #pragma unroll
    for (int j = 0; j < 4; ++j) acc[j] = (f32x4)0.f;
    #pragma unroll
    for (int ks = 0; ks < 4; ++ks)
      #pragma unroll
      for (int j = 0; j < 4; ++j) {
        s16x8 bf = *(const s16x8*)(gs + SW16(j * 16 + lo, ks * 4 + quad));
        acc[j] = __builtin_amdgcn_mfma_f32_16x16x32_bf16(af[ks], bf, acc[j], 0, 0, 0);
      }
    #pragma unroll
    for (int r = 0; r < 4; ++r) {
      float vmax = fmaxf(fmaxf(acc[0][r], acc[1][r]), fmaxf(acc[2][r], acc[3][r]));
      float mn = fmaxf(mloc[r], vmax);
      lloc[r] = lloc[r] * __expf(mloc[r] - mn) +
                __expf(acc[0][r] - mn) + __expf(acc[1][r] - mn) +
                __expf(acc[2][r] - mn) + __expf(acc[3][r] - mn);
      mloc[r] = mn;
    }
  }
  // cross-lane merge over the 16 lanes sharing a row
  #pragma unroll
  for (int r = 0; r < 4; ++r) {
    #pragma unroll
    for (int o = 1; o < 16; o <<= 1) {
      float mo = __shfl_xor(mloc[r], o, 64);
      float lo2 = __shfl_xor(lloc[r], o, 64);
      float mn = fmaxf(mloc[r], mo);
      lloc[r] = lloc[r] * __expf(mloc[r] - mn) + lo2 * __expf(mo - mn);
      mloc[r] = mn;
    }
  }
  if (lo == 0) {
    #pragma unroll
    for (int r = 0; r < 4; ++r)
      pstats[((size_t)mz * B_ + b) * N_ + n0 + w * 16 + quad * 4 + r] =
          make_float2(mloc[r], lloc[r]);
  }
}

// ---------------- merge 4 partial stats -> final (mx, l) --------------------
__global__ __launch_bounds__(256) void k_stats_red(const float2* __restrict__ p,
                                                   float2* __restrict__ stats) {
  int idx = blockIdx.x * 256 + threadIdx.x;   // b*N+n
  if (idx >= B_ * N_) return;
  float mx = -1e30f, ls = 0.f;
  #pragma unroll
  for (int z = 0; z < 4; ++z) {
    float2 s = p[(size_t)z * B_ * N_ + idx];
    float mn = fmaxf(mx, s.x);
    ls = ls * __expf(mx - mn) + s.y * __expf(s.x - mn);
    mx = mn;
  }
  stats[idx] = make_float2(mx, ls);
}

// ------- pass 2: fused scores+softmax+PV partials; grid 1152 (XCD swizzle) --
// g staged in LDS (not registers) -> low VGPR, high occupancy
__global__ __launch_bounds__(256) void k_attn_out(const ushort* __restrict__ f,
                                                  const ushort* __restrict__ g,
                                                  const ushort* __restrict__ h,
                                                  const float2* __restrict__ stats,
                                                  float* __restrict__ spart) {
  __shared__ __align__(16) char smem[35072];
  char* gs = smem;            // [64 m][128 c] SW16 16 KB (staged once)
  char* pTb = smem + 16384;   // pT double buffer 2 x 8 KB
  const int blk = blockIdx.x;
  const int b = blk & 7, t2 = blk >> 3;
  const int m0 = (t2 % 36) * 64, nz = t2 / 36;
  const int t = threadIdx.x, l = t & 63, w = t >> 6, lo = l & 15, quad = l >> 4;
  const ushort* fb = f + (size_t)b * N_ * C_;
  const ushort* gb = g + (size_t)b * N_ * C_;
  const ushort* hb = h + (size_t)b * C_ * N_;
  const float2* stb = stats + (size_t)b * N_;
  #pragma unroll
  for (int it = 0; it < 4; ++it) {   // gs: 1024 granules, once
    int G = t + it * 256, row = G >> 4, g16 = G & 15;
    *(u16x8*)(gs + SW16(row, g16)) = *(const u16x8*)(gb + (size_t)(m0 + row) * C_ + g16 * 8);
  }
  __syncthreads();
  f32x4 accs[2][4];
  #pragma unroll
  for (int i = 0; i < 2; ++i)
    #pragma unroll
    for (int j = 0; j < 4; ++j) accs[i][j] = (f32x4)0.f;
  const int n_beg = nz * 576;

  for (int i9 = 0; i9 < 9; ++i9) {
    int nb = n_beg + i9 * 64;
    char* pT = pTb + ((i9 & 1) << 13);
    s16x8 af[4], ah[2][2];
    #pragma unroll
    for (int ks = 0; ks < 4; ++ks)
      af[ks] = *(const s16x8*)(fb + (size_t)(nb + w * 16 + lo) * C_ + (ks * 4 + quad) * 8);
    #pragma unroll
    for (int i = 0; i < 2; ++i)
      #pragma unroll
      for (int ks = 0; ks < 2; ++ks)
        ah[i][ks] = *(const s16x8*)(hb + (size_t)((2 * w + i) * 16 + lo) * N_ + nb + (ks * 4 + quad) * 8);
    f32x4 sc[4];
    #pragma unroll
    for (int j = 0; j < 4; ++j) sc[j] = (f32x4)0.f;
    #pragma unroll
    for (int ks = 0; ks < 4; ++ks)
      #pragma unroll
      for (int j = 0; j < 4; ++j) {
        s16x8 bg = *(const s16x8*)(gs + SW16(j * 16 + lo, ks * 4 + quad));
        sc[j] = __builtin_amdgcn_mfma_f32_16x16x32_bf16(af[ks], bg, sc[j], 0, 0, 0);
      }
    float mxr[4], ilr[4];
    #pragma unroll
    for (int r = 0; r < 4; ++r) {
      float2 st = stb[nb + w * 16 + quad * 4 + r];
      mxr[r] = st.x; ilr[r] = 1.f / st.y;
    }
    const int nl = w * 16 + quad * 4;
    #pragma unroll
    for (int j = 0; j < 4; ++j) {
      u16x4 pv;
      #pragma unroll
      for (int r = 0; r < 4; ++r)
        pv[r] = f2bf(__expf(sc[j][r] - mxr[r]) * ilr[r]);
      *(u16x4*)(pT + SW8(j * 16 + lo, nl >> 3) + (nl & 7) * 2) = pv;
    }
    __syncthreads();
    #pragma unroll
    for (int ks = 0; ks < 2; ++ks)
      #pragma unroll
      for (int j = 0; j < 4; ++j) {
        s16x8 bp = *(const s16x8*)(pT + SW8(j * 16 + lo, ks * 4 + quad));
        accs[0][j] = __builtin_amdgcn_mfma_f32_16x16x32_bf16(ah[0][ks], bp, accs[0][j], 0, 0, 0);
        accs[1][j] = __builtin_amdgcn_mfma_f32_16x16x32_bf16(ah[1][ks], bp, accs[1][j], 0, 0, 0);
      }
  }
  __syncthreads();
  float* ss = (float*)smem;   // [128 c][68]
  #pragma unroll
  for (int i = 0; i < 2; ++i) {
    int c0 = (2 * w + i) * 16 + quad * 4;
    #pragma unroll
    for (int j = 0; j < 4; ++j) {
      int m = j * 16 + lo;
      #pragma unroll
      for (int r = 0; r < 4; ++r)
        ss[(c0 + r) * 68 + m] = accs[i][j][r];
    }
  }
  __syncthreads();
  float* outp = spart + (size_t)nz * TOT_OUT + (size_t)b * C_ * N_ + m0;
  #pragma unroll
  for (int it = 0; it < 8; ++it) {
    int idx = t + it * 256;
    int c = idx >> 4, mq = idx & 15;
    float4 v = *(const float4*)&ss[c * 68 + mq * 4];
    *(float4*)&outp[(size_t)c * N_ + mq * 4] = v;
  }
}

// ---------------- sbuf = gamma * sum_z spart[z] -----------------------------
__global__ __launch_bounds__(256) void k_sred(const float* __restrict__ spart,
                                              const float* __restrict__ gammap,
                                              float* __restrict__ sbuf) {
  int idx = blockIdx.x * 256 + threadIdx.x;
  if (idx >= TOT_OUT) return;
  float s = spart[idx] + spart[(size_t)TOT_OUT + idx] +
            spart[2 * (size_t)TOT_OUT + idx] + spart[3 * (size_t)TOT_OUT + idx];
  sbuf[idx] = gammap[0] * s;
}

// ---------------- ws = relu(mean_m s) ---------------------------------------
__global__ __launch_bounds__(256) void k_means(const float* __restrict__ s,
                                               float* __restrict__ wcat) {
  int bc = blockIdx.x;
  const float* p = s + (size_t)bc * N_;
  float sm = 0.f;
  for (int i = threadIdx.x; i < N_; i += 256) sm += p[i];
  sm = block_reduce_sum_256(sm);
  if (threadIdx.x == 0) {
    int b = bc >> 7, c = bc & 127;
    wcat[b * 256 + 128 + c] = fmaxf(sm * (1.f / N_), 0.f);
  }
}

// ---------------- SE MLP: 256 -> 42 (relu) -> 128 ---------------------------
__global__ __launch_bounds__(128) void k_se(const float* __restrict__ wcat,
                                            const float* __restrict__ cw,
                                            const float* __restrict__ cb,
                                            const float* __restrict__ uw,
                                            const float* __restrict__ ub,
                                            float* __restrict__ se) {
  const int b = blockIdx.x, t = threadIdx.x;
  __shared__ float wc[256];
  __shared__ float s1[42];
  wc[t] = wcat[b * 256 + t];
  wc[128 + t] = wcat[b * 256 + 128 + t];
  __syncthreads();
  if (t < 42) {
    float a = cb[t];
    const float* r = cw + (size_t)t * 256;
    for (int k = 0; k < 256; ++k) a += wc[k] * r[k];
    s1[t] = fmaxf(a, 0.f);
  }
  __syncthreads();
  {
    float a = ub[t];
    const float* r = uw + (size_t)t * 42;
    for (int j = 0; j < 42; ++j) a += s1[j] * r[j];
    se[b * 128 + t] = a;
  }
}

// ---------------- out = (avgpool2x2(x) + s) * (1 + se) ----------------------
__global__ __launch_bounds__(256) void k_final(const float* __restrict__ x,
                                               const float* __restrict__ s,
                                               const float* __restrict__ se,
                                               float* __restrict__ out) {
  int idx = blockIdx.x * 256 + threadIdx.x;
  if (idx >= TOT_OUT) return;
  int m  = idx % N_;
  int bc = idx / N_;
  int oh = m / HO_, ow = m - oh * HO_;
  const float* xp = x + (size_t)bc * PLANE_IN;
  int ih = oh * 2, iw = ow * 2;
  float l = 0.25f * (xp[ih * W_ + iw] + xp[ih * W_ + iw + 1] +
                     xp[(ih + 1) * W_ + iw] + xp[(ih + 1) * W_ + iw + 1]);
  out[idx] = (l + s[idx]) * (1.f + se[bc]);
}

extern "C" void kernel_launch(void* const* d_in, const int* in_sizes, int n_in,
                              void* d_out, int out_size, void* d_ws, size_t ws_size,
                              hipStream_t stream) {
  (void)in_sizes; (void)n_in; (void)out_size; (void)ws_size;
  const float* x    = (const float*)d_in[0];
  const float* bnw[3] = {(const float*)d_in[1],  (const float*)d_in[7],  (const float*)d_in[13]};
  const float* bnb[3] = {(const float*)d_in[2],  (const float*)d_in[8],  (const float*)d_in[14]};
  const float* bnm[3] = {(const float*)d_in[3],  (const float*)d_in[9],  (const float*)d_in[15]};
  const float* bnv[3] = {(const float*)d_in[4],  (const float*)d_in[10], (const float*)d_in[16]};
  const float* cw_[3] = {(const float*)d_in[5],  (const float*)d_in[11], (const float*)d_in[17]};
  const float* cbb[3] = {(const float*)d_in[6],  (const float*)d_in[12], (const float*)d_in[18]};
  const float* secw = (const float*)d_in[19];
  const float* secb = (const float*)d_in[20];
  const float* seuw = (const float*)d_in[21];
  const float* seub = (const float*)d_in[22];
  const float* gamma = (const float*)d_in[23];
  float* out = (float*)d_out;

  char* ws = (char*)d_ws;
  size_t off = 0;
  auto alloc = [&](size_t bytes) -> char* {
    char* p = ws + off;
    off = (off + bytes + 255) & ~(size_t)255;
    return p;
  };
  ushort* yp[3];
  for (int p = 0; p < 3; ++p) yp[p] = (ushort*)alloc((size_t)B_ * HP_ * HP_ * C_ * 2);
  ushort* wb[3];
  for (int p = 0; p < 3; ++p) wb[p] = (ushort*)alloc((size_t)C_ * K_CONV * 2);
  ushort* fbuf = (ushort*)alloc((size_t)B_ * N_ * C_ * 2);       // [b][n][c]
  ushort* gbuf = (ushort*)alloc((size_t)B_ * N_ * C_ * 2);       // [b][n][c]
  ushort* hbuf = (ushort*)alloc((size_t)B_ * C_ * N_ * 2);       // [b][c][n]
  float2* pstats = (float2*)alloc((size_t)4 * B_ * N_ * 8);      // partial (mx,l)
  float2* stats  = (float2*)alloc((size_t)B_ * N_ * 8);          // final (mx,l)
  float*  spart = (float*)alloc((size_t)4 * TOT_OUT * 4);        // partial PV sums
  float*  sbuf = (float*)alloc((size_t)TOT_OUT * 4);             // [b][c][n]
  float*  wcat = (float*)alloc(B_ * 256 * 4);
  float*  sebuf = (float*)alloc(B_ * 128 * 4);
  float*  pinv  = (float*)alloc(3 * 128 * 4);
  float*  pbeta = (float*)alloc(3 * 128 * 4);

  k_prep<<<3, 128, 0, stream>>>(bnw[0], bnb[0], bnm[0], bnv[0],
                                bnw[1], bnb[1], bnm[1], bnv[1],
                                bnw[2], bnb[2], bnm[2], bnv[2], pinv, pbeta);
  k_prep_w<<<dim3((C_ * K_CONV + 255) / 256, 3), 256, 0, stream>>>(
      cw_[0], cw_[1], cw_[2], wb[0], wb[1], wb[2]);
  k_prep_y<<<dim3(HP_, B_), 256, 0, stream>>>(x, pinv, pbeta, yp[0], yp[1], yp[2]);
  k_meanx<<<B_ * C_, 256, 0, stream>>>(x, wcat);

  k_conv3<<<dim3(N_ / 64, 3, B_), 256, 0, stream>>>(yp[0], yp[1], yp[2],
                                                    wb[0], wb[1], wb[2],
                                                    cbb[0], cbb[1], cbb[2],
                                                    fbuf, gbuf, hbuf);

  k_stats<<<1152, 256, 0, stream>>>(fbuf, gbuf, pstats);
  k_stats_red<<<(B_ * N_ + 255) / 256, 256, 0, stream>>>(pstats, stats);
  k_attn_out<<<1152, 256, 0, stream>>>(fbuf, gbuf, hbuf, stats, spart);
  k_sred<<<(TOT_OUT + 255) / 256, 256, 0, stream>>>(spart, gamma, sbuf);

  k_means<<<B_ * C_, 256, 0, stream>>>(sbuf, wcat);
  k_se<<<B_, 128, 0, stream>>>(wcat, secw, secb, seuw, seub, sebuf);

  k_final<<<(TOT_OUT + 255) / 256, 256, 0, stream>>>(x, sbuf, sebuf, out);
}